// Round 6
// baseline (23480.107 us; speedup 1.0000x reference)
//
#include <hip/hip_runtime.h>

// ---------------------------------------------------------------- types
typedef __bf16 bf16_t;
typedef bf16_t bf16x8 __attribute__((ext_vector_type(8)));
typedef bf16_t bf16x4 __attribute__((ext_vector_type(4)));
typedef float  f32x4  __attribute__((ext_vector_type(4)));

#define MFMA16(a,b,c) __builtin_amdgcn_mfma_f32_16x16x32_bf16((a),(b),(c),0,0,0)

#define TSTEPS 64
#define NB     512
#define GRID   256
#define DIN    556
#define LDSK   40   // LDS row stride (bf16): 80B rows -> <=2-way bank aliasing (free)

// bf16 weight-pool element offsets
#define OFF_WIHP_L 0u
#define OFF_WHH_L  327680u
#define OFF_WIHP_A 589824u
#define OFF_WHH_A  655360u
#define OFF_WIHP_V 720896u
#define OFF_WHH_V  786432u
#define OFF_ATT1W1 851968u
#define OFF_ATT1W2 1376256u
#define OFF_ATT2W1 1900544u
#define OFF_ATT2W2 2424832u
#define OFF_G1W1   2555904u
#define OFF_G1W2   3211264u
#define OFF_G2W1   3342336u
#define OFF_G2W2   3997696u
#define OFF_FLW    4128768u
#define OFF_FAW    4161536u
#define OFF_FVW    4177920u

// ws byte offsets
#define WS_POOL   0
#define WS_XL     8388608
#define WS_XA     29360128
#define WS_XV     37748736
#define WS_HB0    46137344
#define WS_HB1    46661632
#define WS_CBUF   47185920
#define WS_MEMF   48234496
#define WS_MEMBF  48758784
#define WS_CSTAR  49020928
#define WS_Z1     50069504
#define WS_LOGB   50593792
#define WS_ATTD   52690944
#define WS_Z3     53739520
#define WS_PL     55312384
#define WS_MX     56098816
#define WS_BSUM   56099072
#define WS_BAR    56107264

__device__ __forceinline__ float sigmoidf_(float x) {
  return 1.0f / (1.0f + __expf(-x));
}
__device__ __forceinline__ float tanhf_(float x) {
  x = fminf(fmaxf(x, -15.0f), 15.0f);
  float e = __expf(2.0f * x);
  return (e - 1.0f) / (e + 1.0f);
}

// ---------------------------------------------------------------- zero init
__global__ __launch_bounds__(256) void zero_kernel(float4* p, int n4) {
  int i = blockIdx.x * 256 + threadIdx.x;
  if (i < n4) p[i] = make_float4(0.f, 0.f, 0.f, 0.f);
}

// ---------------------------------------------------- convert+pad weights
__global__ __launch_bounds__(256) void cvt_pad_kernel(
    const float* __restrict__ src, bf16_t* __restrict__ dst, int K, int Kpad)
{
  int r = blockIdx.x;
  for (int k = threadIdx.x; k < Kpad; k += 256)
    dst[(size_t)r * Kpad + k] = (k < K) ? (bf16_t)src[(size_t)r * K + k] : (bf16_t)0.f;
}

// ------------------------------------------- split x into per-modality bf16
__global__ __launch_bounds__(256) void cvt_x_kernel(
    const float* __restrict__ x, bf16_t* __restrict__ xl,
    bf16_t* __restrict__ xa, bf16_t* __restrict__ xv)
{
  int r = blockIdx.x;
  const float* xr = x + (size_t)r * DIN;
  for (int c = threadIdx.x; c < 576; c += 256) {
    if (c < 320) {
      xl[(size_t)r * 320 + c] = (c < 300) ? (bf16_t)xr[c] : (bf16_t)0.f;
    } else if (c < 448) {
      xa[(size_t)r * 128 + (c - 320)] = (bf16_t)xr[300 + (c - 320)];
    } else {
      xv[(size_t)r * 128 + (c - 448)] = (bf16_t)xr[428 + (c - 448)];
    }
  }
}

// --------------------------------------------------------- summed LSTM bias
__global__ __launch_bounds__(256) void bias_sum_kernel(
    const float* __restrict__ bih_l, const float* __restrict__ bhh_l,
    const float* __restrict__ bih_a, const float* __restrict__ bhh_a,
    const float* __restrict__ bih_v, const float* __restrict__ bhh_v,
    float* __restrict__ bsum)
{
  int i = blockIdx.x * 256 + threadIdx.x;
  if (i < 1024)      bsum[i] = bih_l[i] + bhh_l[i];
  else if (i < 1536) bsum[i] = bih_a[i - 1024] + bhh_a[i - 1024];
  else if (i < 2048) bsum[i] = bih_v[i - 1536] + bhh_v[i - 1536];
}

// ================================================== grid barrier (manual)
__device__ __noinline__ void gbar(unsigned* cnt, unsigned* gen) {
  __syncthreads();
  __threadfence();
  if (threadIdx.x == 0) {
    unsigned g = atomicAdd(gen, 0u);
    unsigned arrived = atomicAdd(cnt, 1u);
    if (arrived == GRID - 1u) {
      atomicExch(cnt, 0u);
      atomicAdd(gen, 1u);
    } else {
      while (atomicAdd(gen, 0u) == g) {
        __builtin_amdgcn_s_sleep(1);
      }
    }
  }
  __syncthreads();
  __threadfence();
}

// ================================================== phase 1: gates + cell
// 128 tiles (blk<128): 64 rows x 32 j x 4 gates. Body = round-2 kernel.
__device__ __noinline__ void phase_gates(
    const bf16_t* xl_t, const bf16_t* xa_t, const bf16_t* xv_t,
    const bf16_t* hin, bf16_t* hout, float* cbase,
    const bf16_t* pool, const float* bsum, bf16_t* cstar)
{
  __shared__ __align__(16) bf16_t Al[64 * LDSK];
  __shared__ __align__(16) bf16_t Wl[128 * LDSK];
  __shared__ float Gx[4][64][32];

  const int tid = threadIdx.x;
  const int blk = blockIdx.x;
  const int m0 = (blk >> 4) * 64;
  const int y  = blk & 15;

  const bf16_t *xp, *Wih, *Whh;
  int Kx, Hm, hoff, j0, oldbase, boff;
  if (y < 8) {
    xp = xl_t; Wih = pool + OFF_WIHP_L; Whh = pool + OFF_WHH_L;
    Kx = 320; Hm = 256; hoff = 0; j0 = y * 32; oldbase = 0; boff = 0;
  } else if (y < 12) {
    xp = xa_t; Wih = pool + OFF_WIHP_A; Whh = pool + OFF_WHH_A;
    Kx = 128; Hm = 128; hoff = 131072; j0 = (y - 8) * 32; oldbase = 256; boff = 1024;
  } else {
    xp = xv_t; Wih = pool + OFF_WIHP_V; Whh = pool + OFF_WHH_V;
    Kx = 128; Hm = 128; hoff = 196608; j0 = (y - 12) * 32; oldbase = 384; boff = 1536;
  }

  const int wave = tid >> 6, lane = tid & 63;
  const int lrow = lane & 15, quad = lane >> 4;
  const int srow = tid >> 2, schunk = (tid & 3) * 8;
  const int wrow = tid >> 1, wchunk = (tid & 1) * 16;

  f32x4 acc[4][2];
  #pragma unroll
  for (int mi = 0; mi < 4; mi++)
    #pragma unroll
    for (int ni = 0; ni < 2; ni++) acc[mi][ni] = f32x4{0.f, 0.f, 0.f, 0.f};

  for (int ph = 0; ph < 2; ph++) {
    const bf16_t* Ab; const bf16_t* Wb; int lda_, ldw_, K_;
    if (ph == 0) { Ab = xp;          lda_ = Kx; K_ = Kx; Wb = Wih; ldw_ = Kx; }
    else         { Ab = hin + hoff;  lda_ = Hm; K_ = Hm; Wb = Whh; ldw_ = Hm; }

    for (int k0 = 0; k0 < K_; k0 += 32) {
      bf16x8 av = *(const bf16x8*)(Ab + (size_t)(m0 + srow) * lda_ + k0 + schunk);
      int g = wrow >> 5, jr = wrow & 31;
      const bf16_t* wsrc = Wb + (size_t)(g * Hm + j0 + jr) * ldw_ + k0 + wchunk;
      bf16x8 wv0 = *(const bf16x8*)(wsrc);
      bf16x8 wv1 = *(const bf16x8*)(wsrc + 8);
      *(bf16x8*)(Al + srow * LDSK + schunk) = av;
      *(bf16x8*)(Wl + wrow * LDSK + wchunk) = wv0;
      *(bf16x8*)(Wl + wrow * LDSK + wchunk + 8) = wv1;
      __syncthreads();
      bf16x8 afr[4], bfr[2];
      #pragma unroll
      for (int mi = 0; mi < 4; mi++)
        afr[mi] = *(const bf16x8*)(Al + (mi * 16 + lrow) * LDSK + quad * 8);
      #pragma unroll
      for (int ni = 0; ni < 2; ni++)
        bfr[ni] = *(const bf16x8*)(Wl + (wave * 32 + ni * 16 + lrow) * LDSK + quad * 8);
      #pragma unroll
      for (int mi = 0; mi < 4; mi++)
        #pragma unroll
        for (int ni = 0; ni < 2; ni++)
          acc[mi][ni] = MFMA16(afr[mi], bfr[ni], acc[mi][ni]);
      __syncthreads();
    }
  }

  #pragma unroll
  for (int mi = 0; mi < 4; mi++)
    #pragma unroll
    for (int ni = 0; ni < 2; ni++) {
      int col = ni * 16 + lrow;
      float bv = bsum[boff + wave * Hm + j0 + col];
      #pragma unroll
      for (int r = 0; r < 4; r++) {
        Gx[wave][mi * 16 + quad * 4 + r][col] = acc[mi][ni][r] + bv;
      }
    }
  __syncthreads();

  float* cbuf = cbase + hoff;
  int m = tid >> 2, jb = (tid & 3) * 8;
  #pragma unroll
  for (int i = 0; i < 8; i++) {
    int j = jb + i;
    float gi = Gx[0][m][j], gf = Gx[1][m][j], gg = Gx[2][m][j], go = Gx[3][m][j];
    size_t off = (size_t)(m0 + m) * Hm + (j0 + j);
    float c_old = cbuf[off];
    float c2 = sigmoidf_(gf) * c_old + sigmoidf_(gi) * tanhf_(gg);
    float h2 = sigmoidf_(go) * tanhf_(c2);
    cbuf[off] = c2;
    hout[hoff + off] = (bf16_t)h2;
    size_t cs = (size_t)(m0 + m) * 1024 + oldbase + (j0 + j);
    cstar[cs] = (bf16_t)c_old;
    cstar[cs + 512] = (bf16_t)c2;
  }
  __syncthreads();
}

// ================================================== generic 64x64 lin tile
// Body = round-2 mfma_lin_kernel with explicit (m0,n0).
__device__ __noinline__ void phase_lin(
    const bf16_t* A, int lda, const bf16_t* W, int ldw,
    const float* bias, bf16_t* Cb, float* Cf, int ldc,
    int K, int act, int m0, int n0)
{
  __shared__ __align__(16) bf16_t Al[64 * LDSK];
  __shared__ __align__(16) bf16_t Wl[64 * LDSK];
  const int tid = threadIdx.x;
  const int wave = tid >> 6, lane = tid & 63;
  const int wm = (wave >> 1) * 32, wn = (wave & 1) * 32;
  const int lrow = lane & 15, quad = lane >> 4;
  const int srow = tid >> 2, schunk = (tid & 3) * 8;

  f32x4 acc[2][2];
  #pragma unroll
  for (int mi = 0; mi < 2; mi++)
    #pragma unroll
    for (int ni = 0; ni < 2; ni++) acc[mi][ni] = f32x4{0.f, 0.f, 0.f, 0.f};

  for (int k0 = 0; k0 < K; k0 += 32) {
    bf16x8 av = *(const bf16x8*)(A + (size_t)(m0 + srow) * lda + k0 + schunk);
    bf16x8 wv = *(const bf16x8*)(W + (size_t)(n0 + srow) * ldw + k0 + schunk);
    *(bf16x8*)(Al + srow * LDSK + schunk) = av;
    *(bf16x8*)(Wl + srow * LDSK + schunk) = wv;
    __syncthreads();
    bf16x8 a0 = *(const bf16x8*)(Al + (wm + lrow) * LDSK + quad * 8);
    bf16x8 a1 = *(const bf16x8*)(Al + (wm + 16 + lrow) * LDSK + quad * 8);
    bf16x8 b0 = *(const bf16x8*)(Wl + (wn + lrow) * LDSK + quad * 8);
    bf16x8 b1 = *(const bf16x8*)(Wl + (wn + 16 + lrow) * LDSK + quad * 8);
    acc[0][0] = MFMA16(a0, b0, acc[0][0]);
    acc[0][1] = MFMA16(a0, b1, acc[0][1]);
    acc[1][0] = MFMA16(a1, b0, acc[1][0]);
    acc[1][1] = MFMA16(a1, b1, acc[1][1]);
    __syncthreads();
  }
  #pragma unroll
  for (int mi = 0; mi < 2; mi++)
    #pragma unroll
    for (int ni = 0; ni < 2; ni++) {
      int row0 = m0 + wm + mi * 16 + quad * 4;
      int col = n0 + wn + ni * 16 + lrow;
      float bv = bias[col];
      #pragma unroll
      for (int r = 0; r < 4; r++) {
        float v = acc[mi][ni][r] + bv;
        if (act == 1) v = fmaxf(v, 0.f);
        size_t off = (size_t)(row0 + r) * ldc + col;
        if (Cb) Cb[off] = (bf16_t)v;
        if (Cf) Cf[off] = v;
      }
    }
  __syncthreads();
}

// ================================================== phase 4: softmax+attend
__device__ __noinline__ void phase_softmax(
    const float* logits, const bf16_t* cstar, bf16_t* attd)
{
  __shared__ float red[256];
  const int tid = threadIdx.x;
  for (int rr = 0; rr < 2; rr++) {
    int n = blockIdx.x * 2 + rr;
    float4 v = *(const float4*)(logits + (size_t)n * 1024 + tid * 4);
    float mx = fmaxf(fmaxf(v.x, v.y), fmaxf(v.z, v.w));
    red[tid] = mx; __syncthreads();
    for (int s = 128; s > 0; s >>= 1) {
      if (tid < s) red[tid] = fmaxf(red[tid], red[tid + s]);
      __syncthreads();
    }
    mx = red[0]; __syncthreads();
    float e0 = __expf(v.x - mx), e1 = __expf(v.y - mx);
    float e2 = __expf(v.z - mx), e3 = __expf(v.w - mx);
    red[tid] = e0 + e1 + e2 + e3; __syncthreads();
    for (int s = 128; s > 0; s >>= 1) {
      if (tid < s) red[tid] += red[tid + s];
      __syncthreads();
    }
    float inv = 1.0f / red[0];
    __syncthreads();
    bf16x4 c4 = *(const bf16x4*)(cstar + (size_t)n * 1024 + tid * 4);
    bf16x4 o;
    o[0] = (bf16_t)(e0 * inv * (float)c4[0]);
    o[1] = (bf16_t)(e1 * inv * (float)c4[1]);
    o[2] = (bf16_t)(e2 * inv * (float)c4[2]);
    o[3] = (bf16_t)(e3 * inv * (float)c4[3]);
    *(bf16x4*)(attd + (size_t)n * 1024 + tid * 4) = o;
  }
}

// ================================================== phase 5: z3 tile
// Body = round-2 z3_kernel with explicit (m0,n0). 192 tiles.
__device__ __noinline__ void phase_z3(
    const bf16_t* attd, const bf16_t* membf, const bf16_t* pool,
    const float* att2_b1, const float* g1_b1, const float* g2_b1,
    bf16_t* z3, int m0, int n0)
{
  __shared__ __align__(16) bf16_t Al[64 * LDSK];
  __shared__ __align__(16) bf16_t Wl[64 * LDSK];
  const int tid = threadIdx.x;
  const int wave = tid >> 6, lane = tid & 63;
  const int wm = (wave >> 1) * 32, wn = (wave & 1) * 32;
  const int lrow = lane & 15, quad = lane >> 4;
  const int srow = tid >> 2, schunk = (tid & 3) * 8;

  const bf16_t* W; const float* b; int K, nloc;
  if (n0 < 512)       { W = pool + OFF_ATT2W1; b = att2_b1; K = 1024; nloc = n0; }
  else if (n0 < 1024) { W = pool + OFF_G1W1;  b = g1_b1;  K = 1280; nloc = n0 - 512; }
  else                { W = pool + OFF_G2W1;  b = g2_b1;  K = 1280; nloc = n0 - 1024; }

  f32x4 acc[2][2];
  #pragma unroll
  for (int mi = 0; mi < 2; mi++)
    #pragma unroll
    for (int ni = 0; ni < 2; ni++) acc[mi][ni] = f32x4{0.f, 0.f, 0.f, 0.f};

  for (int k0 = 0; k0 < K; k0 += 32) {
    bf16x8 av;
    if (k0 < 1024)
      av = *(const bf16x8*)(attd + (size_t)(m0 + srow) * 1024 + k0 + schunk);
    else
      av = *(const bf16x8*)(membf + (size_t)(m0 + srow) * 256 + (k0 - 1024) + schunk);
    bf16x8 wv = *(const bf16x8*)(W + (size_t)(nloc + srow) * K + k0 + schunk);
    *(bf16x8*)(Al + srow * LDSK + schunk) = av;
    *(bf16x8*)(Wl + srow * LDSK + schunk) = wv;
    __syncthreads();
    bf16x8 a0 = *(const bf16x8*)(Al + (wm + lrow) * LDSK + quad * 8);
    bf16x8 a1 = *(const bf16x8*)(Al + (wm + 16 + lrow) * LDSK + quad * 8);
    bf16x8 b0 = *(const bf16x8*)(Wl + (wn + lrow) * LDSK + quad * 8);
    bf16x8 b1 = *(const bf16x8*)(Wl + (wn + 16 + lrow) * LDSK + quad * 8);
    acc[0][0] = MFMA16(a0, b0, acc[0][0]);
    acc[0][1] = MFMA16(a0, b1, acc[0][1]);
    acc[1][0] = MFMA16(a1, b0, acc[1][0]);
    acc[1][1] = MFMA16(a1, b1, acc[1][1]);
    __syncthreads();
  }
  #pragma unroll
  for (int mi = 0; mi < 2; mi++)
    #pragma unroll
    for (int ni = 0; ni < 2; ni++) {
      int row0 = m0 + wm + mi * 16 + quad * 4;
      int cloc = wn + ni * 16 + lrow;
      float bv = b[nloc + cloc];
      #pragma unroll
      for (int r = 0; r < 4; r++) {
        float v = fmaxf(acc[mi][ni][r] + bv, 0.f);
        z3[(size_t)(row0 + r) * 1536 + n0 + cloc] = (bf16_t)v;
      }
    }
  __syncthreads();
}

// ================================================== phase 6: gmem tile
// Body = round-2 gmem_kernel with explicit (m0,n0). 32 tiles.
__device__ __noinline__ void phase_gmem(
    const bf16_t* z3, const bf16_t* pool,
    const float* att2_b2, const float* g1_b2, const float* g2_b2,
    float* memf, bf16_t* membf, int m0, int n0)
{
  __shared__ __align__(16) bf16_t Az[3][64 * LDSK];
  __shared__ __align__(16) bf16_t Wz[3][64 * LDSK];
  const int tid = threadIdx.x;
  const int wave = tid >> 6, lane = tid & 63;
  const int wm = (wave >> 1) * 32, wn = (wave & 1) * 32;
  const int lrow = lane & 15, quad = lane >> 4;
  const int srow = tid >> 2, schunk = (tid & 3) * 8;

  const bf16_t* Ws0 = pool + OFF_ATT2W2;
  const bf16_t* Ws1 = pool + OFF_G1W2;
  const bf16_t* Ws2 = pool + OFF_G2W2;

  f32x4 acc[3][2][2];
  #pragma unroll
  for (int s = 0; s < 3; s++)
    #pragma unroll
    for (int mi = 0; mi < 2; mi++)
      #pragma unroll
      for (int ni = 0; ni < 2; ni++) acc[s][mi][ni] = f32x4{0.f, 0.f, 0.f, 0.f};

  for (int k0 = 0; k0 < 512; k0 += 32) {
    {
      bf16x8 av0 = *(const bf16x8*)(z3 + (size_t)(m0 + srow) * 1536 + 0 + k0 + schunk);
      bf16x8 av1 = *(const bf16x8*)(z3 + (size_t)(m0 + srow) * 1536 + 512 + k0 + schunk);
      bf16x8 av2 = *(const bf16x8*)(z3 + (size_t)(m0 + srow) * 1536 + 1024 + k0 + schunk);
      bf16x8 wv0 = *(const bf16x8*)(Ws0 + (size_t)(n0 + srow) * 512 + k0 + schunk);
      bf16x8 wv1 = *(const bf16x8*)(Ws1 + (size_t)(n0 + srow) * 512 + k0 + schunk);
      bf16x8 wv2 = *(const bf16x8*)(Ws2 + (size_t)(n0 + srow) * 512 + k0 + schunk);
      *(bf16x8*)(Az[0] + srow * LDSK + schunk) = av0;
      *(bf16x8*)(Az[1] + srow * LDSK + schunk) = av1;
      *(bf16x8*)(Az[2] + srow * LDSK + schunk) = av2;
      *(bf16x8*)(Wz[0] + srow * LDSK + schunk) = wv0;
      *(bf16x8*)(Wz[1] + srow * LDSK + schunk) = wv1;
      *(bf16x8*)(Wz[2] + srow * LDSK + schunk) = wv2;
    }
    __syncthreads();
    #pragma unroll
    for (int s = 0; s < 3; s++) {
      bf16x8 a0 = *(const bf16x8*)(Az[s] + (wm + lrow) * LDSK + quad * 8);
      bf16x8 a1 = *(const bf16x8*)(Az[s] + (wm + 16 + lrow) * LDSK + quad * 8);
      bf16x8 b0 = *(const bf16x8*)(Wz[s] + (wn + lrow) * LDSK + quad * 8);
      bf16x8 b1 = *(const bf16x8*)(Wz[s] + (wn + 16 + lrow) * LDSK + quad * 8);
      acc[s][0][0] = MFMA16(a0, b0, acc[s][0][0]);
      acc[s][0][1] = MFMA16(a0, b1, acc[s][0][1]);
      acc[s][1][0] = MFMA16(a1, b0, acc[s][1][0]);
      acc[s][1][1] = MFMA16(a1, b1, acc[s][1][1]);
    }
    __syncthreads();
  }
  #pragma unroll
  for (int mi = 0; mi < 2; mi++)
    #pragma unroll
    for (int ni = 0; ni < 2; ni++) {
      int row0 = m0 + wm + mi * 16 + quad * 4;
      int col = n0 + wn + ni * 16 + lrow;
      float bC = att2_b2[col], b1v = g1_b2[col], b2v = g2_b2[col];
      #pragma unroll
      for (int r = 0; r < 4; r++) {
        float cHat = tanhf_(acc[0][mi][ni][r] + bC);
        float g1 = sigmoidf_(acc[1][mi][ni][r] + b1v);
        float g2 = sigmoidf_(acc[2][mi][ni][r] + b2v);
        size_t off = (size_t)(row0 + r) * 256 + col;
        float nm = g1 * memf[off] + g2 * cHat;
        memf[off] = nm;
        membf[off] = (bf16_t)nm;
      }
    }
  __syncthreads();
}

// =============================================== persistent 64-step loop
__global__ __launch_bounds__(256) void loop_kernel(
    char* base,
    const float* att1_b1, const float* att1_b2,
    const float* att2_b1, const float* att2_b2,
    const float* g1_b1,  const float* g1_b2,
    const float* g2_b1,  const float* g2_b2)
{
  const int blk = blockIdx.x;

  bf16_t* POOL  = (bf16_t*)(base + WS_POOL);
  bf16_t* XL    = (bf16_t*)(base + WS_XL);
  bf16_t* XA    = (bf16_t*)(base + WS_XA);
  bf16_t* XV    = (bf16_t*)(base + WS_XV);
  bf16_t* HB0   = (bf16_t*)(base + WS_HB0);
  bf16_t* HB1   = (bf16_t*)(base + WS_HB1);
  float*  CBUF  = (float*) (base + WS_CBUF);
  float*  MEMF  = (float*) (base + WS_MEMF);
  bf16_t* MEMBF = (bf16_t*)(base + WS_MEMBF);
  bf16_t* CSTAR = (bf16_t*)(base + WS_CSTAR);
  bf16_t* Z1    = (bf16_t*)(base + WS_Z1);
  float*  LOGB  = (float*) (base + WS_LOGB);
  bf16_t* ATTD  = (bf16_t*)(base + WS_ATTD);
  bf16_t* Z3    = (bf16_t*)(base + WS_Z3);
  float*  BSUM  = (float*) (base + WS_BSUM);
  unsigned* BARC = (unsigned*)(base + WS_BAR);
  unsigned* BARS = (unsigned*)(base + WS_BAR + 4);

  for (int t = 0; t < TSTEPS; t++) {
    const bf16_t* xlt = XL + (size_t)t * NB * 320;
    const bf16_t* xat = XA + (size_t)t * NB * 128;
    const bf16_t* xvt = XV + (size_t)t * NB * 128;
    bf16_t* hin  = (t & 1) ? HB1 : HB0;
    bf16_t* hout = (t & 1) ? HB0 : HB1;

    if (blk < 128)
      phase_gates(xlt, xat, xvt, hin, hout, CBUF, POOL, BSUM, CSTAR);
    gbar(BARC, BARS);

    if (blk < 64)
      phase_lin(CSTAR, 1024, POOL + OFF_ATT1W1, 1024, att1_b1,
                Z1, (float*)0, 512, 1024, 1, (blk >> 3) * 64, (blk & 7) * 64);
    gbar(BARC, BARS);

    if (blk < 128)
      phase_lin(Z1, 512, POOL + OFF_ATT1W2, 512, att1_b2,
                (bf16_t*)0, LOGB, 1024, 512, 0, (blk >> 4) * 64, (blk & 15) * 64);
    gbar(BARC, BARS);

    phase_softmax(LOGB, CSTAR, ATTD);
    gbar(BARC, BARS);

    if (blk < 192)
      phase_z3(ATTD, MEMBF, POOL, att2_b1, g1_b1, g2_b1, Z3,
               (blk / 24) * 64, (blk % 24) * 64);
    gbar(BARC, BARS);

    if (blk < 32)
      phase_gmem(Z3, POOL, att2_b2, g1_b2, g2_b2, MEMF, MEMBF,
                 (blk >> 2) * 64, (blk & 3) * 64);
    gbar(BARC, BARS);
  }
}

// ---------------------------------------------------- generic MFMA lin (epilogue)
__global__ __launch_bounds__(256) void mfma_lin_kernel(
    const bf16_t* __restrict__ A, int lda,
    const bf16_t* __restrict__ W, int ldw,
    const float* __restrict__ bias,
    bf16_t* __restrict__ Cb, float* __restrict__ Cf, int ldc,
    int K, int act)
{
  phase_lin(A, lda, W, ldw, bias, Cb, Cf, ldc, K, act,
            blockIdx.x * 64, blockIdx.y * 64);
}

// ------------------------------------------- global max per modality
__global__ __launch_bounds__(256) void max3_kernel(
    const float* __restrict__ pl, float* __restrict__ maxes)
{
  __shared__ float red[256];
  const int b = blockIdx.x, tid = threadIdx.x;
  float mx = -3.4e38f;
  for (int i = tid; i < NB * 128; i += 256) {
    int n = i >> 7, j = i & 127;
    mx = fmaxf(mx, pl[(size_t)n * 384 + b * 128 + j]);
  }
  red[tid] = mx; __syncthreads();
  for (int s = 128; s > 0; s >>= 1) {
    if (tid < s) red[tid] = fmaxf(red[tid], red[tid + s]);
    __syncthreads();
  }
  if (tid == 0) maxes[b] = red[0];
}

// ----------------------------------------------------- final output per row
__global__ __launch_bounds__(256) void out_kernel(
    const float* __restrict__ pl, const float* __restrict__ maxes,
    const float* __restrict__ memb,
    const float* __restrict__ o_w1, const float* __restrict__ o_b1,
    const float* __restrict__ o_w2, const float* __restrict__ o_b2,
    float* __restrict__ out)
{
  __shared__ float hs[384];
  __shared__ float red[256];
  const int n = blockIdx.x, tid = threadIdx.x;
  float M0 = maxes[0], M1 = maxes[1], M2 = maxes[2];
  for (int idx = tid; idx < 384; idx += 256) {
    float v;
    if (idx < 128) {
      float d0 = pl[(size_t)n * 384 + idx] - M0;
      float d1 = pl[(size_t)n * 384 + 128 + idx] - M1;
      float d2 = pl[(size_t)n * 384 + 256 + idx] - M2;
      v = __expf(d0) * d0 + __expf(d1) * d1 + __expf(d2) * d2;
    } else {
      v = memb[(size_t)n * 256 + idx - 128];
    }
    hs[idx] = v;
  }
  __syncthreads();
  float acc = o_b1[tid];
  const float* wr = o_w1 + (size_t)tid * 384;
  #pragma unroll 4
  for (int k = 0; k < 384; k += 4) {
    float4 w = *(const float4*)(wr + k);
    acc += w.x * hs[k] + w.y * hs[k + 1] + w.z * hs[k + 2] + w.w * hs[k + 3];
  }
  red[tid] = fmaxf(acc, 0.f) * o_w2[tid];
  __syncthreads();
  for (int s = 128; s > 0; s >>= 1) {
    if (tid < s) red[tid] += red[tid + s];
    __syncthreads();
  }
  if (tid == 0) out[n] = red[0] + o_b2[0];
}

// ============================================================ host launcher
extern "C" void kernel_launch(void* const* d_in, const int* in_sizes, int n_in,
                              void* d_out, int out_size, void* d_ws, size_t ws_size,
                              hipStream_t stream)
{
  const float* x      = (const float*)d_in[0];
  const float* Wih_l  = (const float*)d_in[1];
  const float* Whh_l  = (const float*)d_in[2];
  const float* bih_l  = (const float*)d_in[3];
  const float* bhh_l  = (const float*)d_in[4];
  const float* Wih_a  = (const float*)d_in[5];
  const float* Whh_a  = (const float*)d_in[6];
  const float* bih_a  = (const float*)d_in[7];
  const float* bhh_a  = (const float*)d_in[8];
  const float* Wih_v  = (const float*)d_in[9];
  const float* Whh_v  = (const float*)d_in[10];
  const float* bih_v  = (const float*)d_in[11];
  const float* bhh_v  = (const float*)d_in[12];
  const float* att1_w1 = (const float*)d_in[13];
  const float* att1_b1 = (const float*)d_in[14];
  const float* att1_w2 = (const float*)d_in[15];
  const float* att1_b2 = (const float*)d_in[16];
  const float* att2_w1 = (const float*)d_in[17];
  const float* att2_b1 = (const float*)d_in[18];
  const float* att2_w2 = (const float*)d_in[19];
  const float* att2_b2 = (const float*)d_in[20];
  const float* g1_w1  = (const float*)d_in[21];
  const float* g1_b1  = (const float*)d_in[22];
  const float* g1_w2  = (const float*)d_in[23];
  const float* g1_b2  = (const float*)d_in[24];
  const float* g2_w1  = (const float*)d_in[25];
  const float* g2_b1  = (const float*)d_in[26];
  const float* g2_w2  = (const float*)d_in[27];
  const float* g2_b2  = (const float*)d_in[28];
  const float* fl_w   = (const float*)d_in[29];
  const float* fl_b   = (const float*)d_in[30];
  const float* fa_w   = (const float*)d_in[31];
  const float* fa_b   = (const float*)d_in[32];
  const float* fv_w   = (const float*)d_in[33];
  const float* fv_b   = (const float*)d_in[34];
  const float* o_w1   = (const float*)d_in[35];
  const float* o_b1   = (const float*)d_in[36];
  const float* o_w2   = (const float*)d_in[37];
  const float* o_b2   = (const float*)d_in[38];

  char* base = (char*)d_ws;
  bf16_t* POOL  = (bf16_t*)(base + WS_POOL);
  bf16_t* XL    = (bf16_t*)(base + WS_XL);
  bf16_t* XA    = (bf16_t*)(base + WS_XA);
  bf16_t* XV    = (bf16_t*)(base + WS_XV);
  bf16_t* HB0   = (bf16_t*)(base + WS_HB0);
  float*  MEMF  = (float*) (base + WS_MEMF);
  float*  PL    = (float*) (base + WS_PL);
  float*  MX    = (float*) (base + WS_MX);
  float*  BSUM  = (float*) (base + WS_BSUM);

  // zero: states (HB0..MEMBF contiguous = 180224 float4) + barrier (1 float4)
  zero_kernel<<<704, 256, 0, stream>>>((float4*)HB0, 180224);
  zero_kernel<<<1, 256, 0, stream>>>((float4*)(base + WS_BAR), 1);

  // conversions
  cvt_x_kernel<<<TSTEPS * NB, 256, 0, stream>>>(x, XL, XA, XV);
  cvt_pad_kernel<<<1024, 256, 0, stream>>>(Wih_l, POOL + OFF_WIHP_L, 300, 320);
  cvt_pad_kernel<<<1024, 256, 0, stream>>>(Whh_l, POOL + OFF_WHH_L, 256, 256);
  cvt_pad_kernel<<<512, 256, 0, stream>>>(Wih_a, POOL + OFF_WIHP_A, 128, 128);
  cvt_pad_kernel<<<512, 256, 0, stream>>>(Whh_a, POOL + OFF_WHH_A, 128, 128);
  cvt_pad_kernel<<<512, 256, 0, stream>>>(Wih_v, POOL + OFF_WIHP_V, 128, 128);
  cvt_pad_kernel<<<512, 256, 0, stream>>>(Whh_v, POOL + OFF_WHH_V, 128, 128);
  cvt_pad_kernel<<<512, 256, 0, stream>>>(att1_w1, POOL + OFF_ATT1W1, 1024, 1024);
  cvt_pad_kernel<<<1024, 256, 0, stream>>>(att1_w2, POOL + OFF_ATT1W2, 512, 512);
  cvt_pad_kernel<<<512, 256, 0, stream>>>(att2_w1, POOL + OFF_ATT2W1, 1024, 1024);
  cvt_pad_kernel<<<256, 256, 0, stream>>>(att2_w2, POOL + OFF_ATT2W2, 512, 512);
  cvt_pad_kernel<<<512, 256, 0, stream>>>(g1_w1, POOL + OFF_G1W1, 1280, 1280);
  cvt_pad_kernel<<<256, 256, 0, stream>>>(g1_w2, POOL + OFF_G1W2, 512, 512);
  cvt_pad_kernel<<<512, 256, 0, stream>>>(g2_w1, POOL + OFF_G2W1, 1280, 1280);
  cvt_pad_kernel<<<256, 256, 0, stream>>>(g2_w2, POOL + OFF_G2W2, 512, 512);
  cvt_pad_kernel<<<128, 256, 0, stream>>>(fl_w, POOL + OFF_FLW, 256, 256);
  cvt_pad_kernel<<<128, 256, 0, stream>>>(fa_w, POOL + OFF_FAW, 128, 128);
  cvt_pad_kernel<<<128, 256, 0, stream>>>(fv_w, POOL + OFF_FVW, 128, 128);
  bias_sum_kernel<<<8, 256, 0, stream>>>(bih_l, bhh_l, bih_a, bhh_a,
                                         bih_v, bhh_v, BSUM);

  // persistent loop: 256 blocks x 256 threads, 1 block/CU (co-resident)
  loop_kernel<<<GRID, 256, 0, stream>>>(base,
                                        att1_b1, att1_b2, att2_b1, att2_b2,
                                        g1_b1, g1_b2, g2_b1, g2_b2);

  // epilogue
  bf16_t* h_l = HB0;               // t=63 wrote HB0
  bf16_t* h_a = HB0 + 131072;
  bf16_t* h_v = HB0 + 196608;

  mfma_lin_kernel<<<dim3(8, 2), 256, 0, stream>>>(
      h_l, 256, POOL + OFF_FLW, 256, fl_b, (bf16_t*)nullptr, PL, 384, 256, 0);
  mfma_lin_kernel<<<dim3(8, 2), 256, 0, stream>>>(
      h_a, 128, POOL + OFF_FAW, 128, fa_b, (bf16_t*)nullptr, PL + 128, 384, 128, 0);
  mfma_lin_kernel<<<dim3(8, 2), 256, 0, stream>>>(
      h_v, 128, POOL + OFF_FVW, 128, fv_b, (bf16_t*)nullptr, PL + 256, 384, 128, 0);
  max3_kernel<<<3, 256, 0, stream>>>(PL, MX);
  out_kernel<<<512, 256, 0, stream>>>(PL, MX, MEMF, o_w1, o_b1, o_w2, o_b2,
                                      (float*)d_out);
}